// Round 4
// baseline (191.831 us; speedup 1.0000x reference)
//
#include <hip/hip_runtime.h>
#include <hip/hip_bf16.h>

// MultiLatentAttention on MI355X.
// causal mask t<=l with L=64 => attention only over first 64 tokens.
// out[b] = softmax_groups(x@Wg) @ M[b],  M built from attn_out and Wp.

typedef __attribute__((ext_vector_type(8))) short bf16x8;
typedef __attribute__((ext_vector_type(4))) float f32x4;
typedef __attribute__((ext_vector_type(4))) unsigned short us4;

__device__ __forceinline__ void gll16(const void* g, void* l) {
  __builtin_amdgcn_global_load_lds((const __attribute__((address_space(1))) void*)g,
                                   (__attribute__((address_space(3))) void*)l, 16, 0, 0);
}

// ---------------- x (fp32) -> bf16 ----------------
__global__ void cvt_x_kernel(const float* __restrict__ x, __hip_bfloat16* __restrict__ xb, int n4) {
  int stride = gridDim.x * blockDim.x;
  for (int i = blockIdx.x * blockDim.x + threadIdx.x; i < n4; i += stride) {
    float4 f = reinterpret_cast<const float4*>(x)[i];
    union { __hip_bfloat16 h[4]; us4 v; } u;
    u.h[0] = __float2bfloat16(f.x);
    u.h[1] = __float2bfloat16(f.y);
    u.h[2] = __float2bfloat16(f.z);
    u.h[3] = __float2bfloat16(f.w);
    reinterpret_cast<us4*>(xb)[i] = u.v;
  }
}

// ---------------- 3 weight transposes fp32->bf16 in one launch ----------------
__global__ void transpose_cvt3(const float* __restrict__ Wg, const float* __restrict__ Wk,
                               const float* __restrict__ Wv,
                               __hip_bfloat16* __restrict__ WgT, __hip_bfloat16* __restrict__ WkT,
                               __hip_bfloat16* __restrict__ WvT) {
  const int n = 1024;
  const float* W;
  __hip_bfloat16* Wt;
  if (blockIdx.z == 0)      { W = Wg; Wt = WgT; }
  else if (blockIdx.z == 1) { W = Wk; Wt = WkT; }
  else                      { W = Wv; Wt = WvT; }
  __shared__ float tile[32][33];
  int bx = blockIdx.x * 32, by = blockIdx.y * 32;
  int tx = threadIdx.x, ty = threadIdx.y;  // block (32,8)
  #pragma unroll
  for (int j = 0; j < 32; j += 8)
    tile[ty + j][tx] = W[(size_t)(by + ty + j) * n + bx + tx];
  __syncthreads();
  #pragma unroll
  for (int j = 0; j < 32; j += 8)
    Wt[(size_t)(bx + ty + j) * n + by + tx] = __float2bfloat16(tile[tx][ty + j]);
}

// ---------------- 256x256 8-phase pipelined bf16 GEMM: C = A @ Bt^T ----------------
// 8 waves (2Mx4N), BK=64, double-buffered 128KiB LDS. Per main iteration: 2 K-tiles,
// 8 phases; each phase = {12 ds_read (quadrant frags) || stage 1 half-tile (2 gll16)
// -> s_barrier -> setprio(1) 16 MFMA setprio(0) -> [vmcnt(2) @P4/P8] -> s_barrier}.
// Stage slots (iter i computes T0=2i buf0, T1=2i+1 buf1):
//   P1: T1.B1  P2: T1.A0  P3: T1.A1  P4: T2.B0 +vm  P5: T2.B1  P6: T2.A0  P7: T2.A1  P8: T3.B0 +vm
// FIFO vmcnt(2) at P4 guarantees T1.{A0,A1,B0} landed before P5; at P8 guarantees
// T2.{A0,A1,B0} before next P1. Region write-after-read windows verified per phase.
// LDS swizzle: 16B-chunk ^= (row&7), pre-swizzled on the GLOBAL source, applied on reads.
// EPI=0: fp32 store. EPI=1: per-64-column-group softmax, bf16 store (gates).

#define VMC2 asm volatile("s_waitcnt vmcnt(2)" ::: "memory")
#define SBAR do { __builtin_amdgcn_sched_barrier(0); __builtin_amdgcn_s_barrier(); \
                  __builtin_amdgcn_sched_barrier(0); } while (0)

#define PHASE(BUF, QM, QN, STAGE_STMT, VM_STMT) do {                                  \
    bf16x8 afr[4][2], bfr[2][2];                                                      \
    _Pragma("unroll") for (int i_ = 0; i_ < 4; ++i_)                                  \
      _Pragma("unroll") for (int kk_ = 0; kk_ < 2; ++kk_) {                           \
        int row_ = wm * 128 + ((QM) * 4 + i_) * 16 + lr;                              \
        int ch_ = (kk_ * 4 + lk) ^ (row_ & 7);                                        \
        afr[i_][kk_] = *(const bf16x8*)&SA[BUF][row_ * 64 + ch_ * 8];                 \
      }                                                                               \
    _Pragma("unroll") for (int j_ = 0; j_ < 2; ++j_)                                  \
      _Pragma("unroll") for (int kk_ = 0; kk_ < 2; ++kk_) {                           \
        int row_ = wn * 64 + ((QN) * 2 + j_) * 16 + lr;                               \
        int ch_ = (kk_ * 4 + lk) ^ (row_ & 7);                                        \
        bfr[j_][kk_] = *(const bf16x8*)&SB[BUF][row_ * 64 + ch_ * 8];                 \
      }                                                                               \
    STAGE_STMT;                                                                       \
    SBAR;                                                                             \
    __builtin_amdgcn_s_setprio(1);                                                    \
    _Pragma("unroll") for (int kk_ = 0; kk_ < 2; ++kk_)                               \
      _Pragma("unroll") for (int i_ = 0; i_ < 4; ++i_)                                \
        _Pragma("unroll") for (int j_ = 0; j_ < 2; ++j_)                              \
          acc[(QM) * 4 + i_][(QN) * 2 + j_] = __builtin_amdgcn_mfma_f32_16x16x32_bf16(\
              afr[i_][kk_], bfr[j_][kk_], acc[(QM) * 4 + i_][(QN) * 2 + j_], 0, 0, 0);\
    __builtin_amdgcn_s_setprio(0);                                                    \
    VM_STMT;                                                                          \
    SBAR;                                                                             \
  } while (0)

template <int EPI>
__global__ __launch_bounds__(512, 2)
void gemm256(const __hip_bfloat16* __restrict__ A, const __hip_bfloat16* __restrict__ Bt,
             void* __restrict__ Cv, int K, int ldc,
             long long astride, long long bstride, long long cstride) {
  __shared__ __align__(16) unsigned short SA[2][256 * 64];
  __shared__ __align__(16) unsigned short SB[2][256 * 64];
  const int tid = threadIdx.x;
  const int lane = tid & 63;
  const int w = tid >> 6;            // wave 0..7
  const int wm = w >> 2, wn = w & 3; // 2x4 wave grid; per-wave out = 128x64
  const int lr = lane & 15, lk = lane >> 4;
  const int m0 = blockIdx.x * 256, n0 = blockIdx.y * 256;
  const long long b = blockIdx.z;
  const __hip_bfloat16* Ab = A + b * astride;
  const __hip_bfloat16* Bb = Bt + b * bstride;

  f32x4 acc[8][4] = {};

  // A half h: chunks h*1024 + r*512 + tid  (rows h*128..h*128+127)
  auto stageA = [&](int bsel, int kt, int half) {
    #pragma unroll
    for (int r = 0; r < 2; ++r) {
      int c = half * 1024 + r * 512 + tid;
      int row = c >> 3, slot = c & 7;
      int gch = slot ^ (row & 7);
      gll16(Ab + (size_t)(m0 + row) * K + kt + gch * 8, (char*)&SA[bsel][0] + c * 16);
    }
  };
  // B q-half: rows with ((row>>5)&1)==q, i.e. chunks j*512 + q*256 + (tid&255), j=r*2+(tid>>8)
  auto stageB = [&](int bsel, int kt, int q) {
    #pragma unroll
    for (int r = 0; r < 2; ++r) {
      int j = r * 2 + (tid >> 8);
      int c = j * 512 + q * 256 + (tid & 255);
      int row = c >> 3, slot = c & 7;
      int gch = slot ^ (row & 7);
      gll16(Bb + (size_t)(n0 + row) * K + kt + gch * 8, (char*)&SB[bsel][0] + c * 16);
    }
  };

  const int NITER = K >> 7;  // 2 K-tiles per iteration

  // prologue: T0 fully into buf0, T1.B0 into buf1
  stageB(0, 0, 0);
  stageB(0, 0, 1);
  stageA(0, 0, 0);
  stageA(0, 0, 1);
  stageB(1, 64, 0);
  VMC2;  // T0 landed; T1.B0 may remain in flight
  SBAR;

  for (int it = 0; it < NITER; ++it) {
    int t1k = (it * 2 + 1) * 64;
    int t2k = (it * 2 + 2) * 64; if (t2k >= K) t2k -= K;  // wrap: harmless garbage stage
    int t3k = (it * 2 + 3) * 64; if (t3k >= K) t3k -= K;

    PHASE(0, 0, 0, stageB(1, t1k, 1), );
    PHASE(0, 1, 0, stageA(1, t1k, 0), );
    PHASE(0, 0, 1, stageA(1, t1k, 1), );
    PHASE(0, 1, 1, stageB(0, t2k, 0), VMC2);
    PHASE(1, 0, 0, stageB(0, t2k, 1), );
    PHASE(1, 1, 0, stageA(0, t2k, 0), );
    PHASE(1, 0, 1, stageA(0, t2k, 1), );
    PHASE(1, 1, 1, stageB(1, t3k, 0), VMC2);
  }
  asm volatile("s_waitcnt vmcnt(0)" ::: "memory");  // drain tail garbage stages

  if (EPI == 0) {
    float* C = (float*)Cv + b * cstride;
    #pragma unroll
    for (int mi = 0; mi < 8; ++mi) {
      int r = m0 + wm * 128 + mi * 16 + lk * 4;
      #pragma unroll
      for (int ni = 0; ni < 4; ++ni) {
        int c = n0 + wn * 64 + ni * 16 + lr;
        #pragma unroll
        for (int jj = 0; jj < 4; ++jj)
          C[(size_t)(r + jj) * ldc + c] = acc[mi][ni][jj];
      }
    }
  } else {
    // Each wave's 64 columns = one softmax group (head h, l=0..63).
    __hip_bfloat16* C = (__hip_bfloat16*)Cv + b * cstride;
    #pragma unroll
    for (int mi = 0; mi < 8; ++mi) {
      #pragma unroll
      for (int jj = 0; jj < 4; ++jj) {
        float mx = -3.0e38f;
        #pragma unroll
        for (int ni = 0; ni < 4; ++ni) mx = fmaxf(mx, acc[mi][ni][jj]);
        mx = fmaxf(mx, __shfl_xor(mx, 1));
        mx = fmaxf(mx, __shfl_xor(mx, 2));
        mx = fmaxf(mx, __shfl_xor(mx, 4));
        mx = fmaxf(mx, __shfl_xor(mx, 8));
        float e[4];
        float s = 0.f;
        #pragma unroll
        for (int ni = 0; ni < 4; ++ni) { e[ni] = __expf(acc[mi][ni][jj] - mx); s += e[ni]; }
        s += __shfl_xor(s, 1);
        s += __shfl_xor(s, 2);
        s += __shfl_xor(s, 4);
        s += __shfl_xor(s, 8);
        float inv = 1.0f / s;
        int r = m0 + wm * 128 + mi * 16 + lk * 4 + jj;
        #pragma unroll
        for (int ni = 0; ni < 4; ++ni)
          C[(size_t)r * ldc + n0 + wn * 64 + ni * 16 + lr] = __float2bfloat16(e[ni] * inv);
      }
    }
  }
}

// ---------------- 128x128 GEMM (kept for the small kv projection) ----------------
__global__ __launch_bounds__(256)
void gemm_bt(const __hip_bfloat16* __restrict__ A, const __hip_bfloat16* __restrict__ Bt,
             void* __restrict__ Cv, int K, int ldc,
             long long astride, long long bstride, long long cstride) {
  __shared__ __align__(16) unsigned short As[128 * 32];
  __shared__ __align__(16) unsigned short Bs[128 * 32];
  const int tid = threadIdx.x;
  const int lane = tid & 63;
  const int w = tid >> 6;
  const int wm = w >> 1, wn = w & 1;
  const int lr = lane & 15, lk = lane >> 4;
  const int m0 = blockIdx.x * 128, n0 = blockIdx.y * 128;
  const long long b = blockIdx.z;
  const __hip_bfloat16* Ab = A + b * astride;
  const __hip_bfloat16* Bb = Bt + b * bstride;

  f32x4 acc[4][4] = {};
  const int r0 = tid >> 2;
  const int c8 = (tid & 3) * 8;

  for (int kt = 0; kt < K; kt += 32) {
    __syncthreads();
    gll16(Ab + (size_t)(m0 + r0) * K + kt + c8,       (char*)As + (w * 64) * 16);
    gll16(Bb + (size_t)(n0 + r0) * K + kt + c8,       (char*)Bs + (w * 64) * 16);
    gll16(Ab + (size_t)(m0 + 64 + r0) * K + kt + c8,  (char*)As + (256 + w * 64) * 16);
    gll16(Bb + (size_t)(n0 + 64 + r0) * K + kt + c8,  (char*)Bs + (256 + w * 64) * 16);
    __syncthreads();

    bf16x8 af[4], bf[4];
    #pragma unroll
    for (int mi = 0; mi < 4; ++mi)
      af[mi] = *(const bf16x8*)&As[(wm * 64 + mi * 16 + lr) * 32 + lk * 8];
    #pragma unroll
    for (int ni = 0; ni < 4; ++ni)
      bf[ni] = *(const bf16x8*)&Bs[(wn * 64 + ni * 16 + lr) * 32 + lk * 8];
    #pragma unroll
    for (int mi = 0; mi < 4; ++mi)
      #pragma unroll
      for (int ni = 0; ni < 4; ++ni)
        acc[mi][ni] = __builtin_amdgcn_mfma_f32_16x16x32_bf16(af[mi], bf[ni], acc[mi][ni], 0, 0, 0);
  }

  float* C = (float*)Cv + b * cstride;
  #pragma unroll
  for (int mi = 0; mi < 4; ++mi) {
    int r = m0 + wm * 64 + mi * 16 + lk * 4;
    #pragma unroll
    for (int ni = 0; ni < 4; ++ni) {
      int c = n0 + wn * 64 + ni * 16 + lr;
      #pragma unroll
      for (int jj = 0; jj < 4; ++jj)
        C[(size_t)(r + jj) * ldc + c] = acc[mi][ni][jj];
    }
  }
}

// ---------------- attention (RoPE fused into K staging): per (b,h), 64x64 ----------------
__global__ __launch_bounds__(256)
void attn_kernel(const float* __restrict__ kv, const float* __restrict__ lq,
                 float* __restrict__ ao) {
  int h = blockIdx.x, b = blockIdx.y;
  __shared__ float Ks[64][64];
  __shared__ float Vs[64][64];
  __shared__ float S[64][65];   // S[l][t]
  __shared__ float Pt[64][65];  // Pt[t][l]
  const int tid = threadIdx.x;
  const float* kb = kv + (size_t)b * 128 * 2048 + h * 64;
  const float* vb = kb + 1024;

  {
    int r = tid >> 4;            // 0..15
    int c4 = (tid & 15) * 4;     // head-dim col (pairs i0=c4/2, i0+1)
    int i0 = c4 >> 1;
    float inv0 = exp2f(-13.287712379549449f * ((float)i0 * (1.0f / 32.0f)));
    float inv1 = exp2f(-13.287712379549449f * ((float)(i0 + 1) * (1.0f / 32.0f)));
    #pragma unroll
    for (int j = 0; j < 4; ++j) {
      int row = j * 16 + r;      // t
      float4 kf = *(const float4*)&kb[(size_t)row * 2048 + c4];
      float a0 = (float)row * inv0, a1 = (float)row * inv1;
      float s0 = sinf(a0), c0 = cosf(a0), s1 = sinf(a1), c1 = cosf(a1);
      *(float4*)&Ks[row][c4] = make_float4(kf.x * c0 - kf.y * s0, kf.x * s0 + kf.y * c0,
                                           kf.z * c1 - kf.w * s1, kf.z * s1 + kf.w * c1);
      *(float4*)&Vs[row][c4] = *(const float4*)&vb[(size_t)row * 2048 + c4];
    }
  }
  __syncthreads();

  // ---- scores: thread = (l = lane, t-chunk = wave) ----
  {
    const int w = tid >> 6, l = tid & 63;
    float q[64];
    const float4* lq4 = (const float4*)(lq + ((size_t)l * 16 + h) * 64);
    #pragma unroll
    for (int i = 0; i < 16; ++i) {
      float4 f = lq4[i];
      q[4 * i] = f.x; q[4 * i + 1] = f.y; q[4 * i + 2] = f.z; q[4 * i + 3] = f.w;
    }
    #pragma unroll
    for (int tl = 0; tl < 16; ++tl) {
      int t = w * 16 + tl;
      float acc = 0.f;
      #pragma unroll
      for (int d4 = 0; d4 < 16; ++d4) {
        float4 kf = *(const float4*)&Ks[t][d4 * 4];
        acc += q[4 * d4] * kf.x + q[4 * d4 + 1] * kf.y + q[4 * d4 + 2] * kf.z + q[4 * d4 + 3] * kf.w;
      }
      S[l][t] = acc * 0.125f;
    }
  }
  __syncthreads();

  // ---- softmax: thread = (l = tid>>2, c = tid&3), causal t<=l ----
  {
    const int l = tid >> 2, c = tid & 3;
    float sv[16];
    float mx = -3.0e38f;
    #pragma unroll
    for (int i = 0; i < 16; ++i) {
      int t = c * 16 + i;
      sv[i] = S[l][t];
      if (t <= l) mx = fmaxf(mx, sv[i]);
    }
    mx = fmaxf(mx, __shfl_xor(mx, 1));
    mx = fmaxf(mx, __shfl_xor(mx, 2));
    float sum = 0.f;
    float e[16];
    #pragma unroll
    for (int i = 0; i < 16; ++i) {
      int t = c * 16 + i;
      e[i] = (t <= l) ? __expf(sv[i] - mx) : 0.f;
      sum += e[i];
    }
    sum += __shfl_xor(sum, 1);
    sum += __shfl_xor(sum, 2);
    float inv = 1.0f / sum;
    #pragma unroll
    for (int i = 0; i < 16; ++i) Pt[c * 16 + i][l] = e[i] * inv;
  }
  __syncthreads();

  // ---- PV: thread = (l = lane, d-chunk = wave) ----
  {
    const int w = tid >> 6, l = tid & 63;
    float o[16];
    #pragma unroll
    for (int i = 0; i < 16; ++i) o[i] = 0.f;
    for (int t = 0; t < 64; ++t) {
      float p = Pt[t][l];
      #pragma unroll
      for (int d4 = 0; d4 < 4; ++d4) {
        float4 vf = *(const float4*)&Vs[t][w * 16 + d4 * 4];
        o[4 * d4]     += p * vf.x;
        o[4 * d4 + 1] += p * vf.y;
        o[4 * d4 + 2] += p * vf.z;
        o[4 * d4 + 3] += p * vf.w;
      }
    }
    float4* dst = (float4*)(ao + (((size_t)b * 16 + h) * 64 + l) * 64 + w * 16);
    #pragma unroll
    for (int d4 = 0; d4 < 4; ++d4)
      dst[d4] = make_float4(o[4 * d4], o[4 * d4 + 1], o[4 * d4 + 2], o[4 * d4 + 3]);
  }
}

// ---------------- Mt[b][c][h*64+l] = sum_d ao[b,h,l,d] * Wp[h*64+d][c]  (bf16) ----------------
__global__ void build_mt(const float* __restrict__ ao, const float* __restrict__ Wp,
                         __hip_bfloat16* __restrict__ Mt) {
  int ct = blockIdx.x;  // 0..3
  int h = blockIdx.y;   // 0..15
  int b = blockIdx.z;   // 0..3
  int c = ct * 256 + threadIdx.x;
  __shared__ float A[64][64];  // ao[l][d]
  const float* aob = ao + (((size_t)b * 16 + h) * 64) * 64;
  for (int i = threadIdx.x; i < 4096; i += 256) A[i >> 6][i & 63] = aob[i];
  __syncthreads();
  for (int lc = 0; lc < 4; ++lc) {
    float acc[16];
    #pragma unroll
    for (int li = 0; li < 16; ++li) acc[li] = 0.f;
    for (int d = 0; d < 64; ++d) {
      float wv = Wp[(size_t)(h * 64 + d) * 1024 + c];
      #pragma unroll
      for (int li = 0; li < 16; ++li) acc[li] += A[lc * 16 + li][d] * wv;
    }
    size_t base = ((size_t)b * 1024 + c) * 1024 + h * 64 + lc * 16;
    #pragma unroll
    for (int li = 0; li < 16; ++li) Mt[base + li] = __float2bfloat16(acc[li]);
  }
}

extern "C" void kernel_launch(void* const* d_in, const int* in_sizes, int n_in,
                              void* d_out, int out_size, void* d_ws, size_t ws_size,
                              hipStream_t stream) {
  const float* x  = (const float*)d_in[0];
  const float* lq = (const float*)d_in[1];
  const float* Wk = (const float*)d_in[2];
  const float* Wv = (const float*)d_in[3];
  const float* Wg = (const float*)d_in[4];
  const float* Wp = (const float*)d_in[5];
  float* out = (float*)d_out;

  // workspace layout (bytes)
  char* w = (char*)d_ws;
  __hip_bfloat16* xb   = (__hip_bfloat16*)(w);              // 33,554,432
  __hip_bfloat16* G    = (__hip_bfloat16*)(w + 33554432);   // 33,554,432
  __hip_bfloat16* WgT  = (__hip_bfloat16*)(w + 67108864);   // 2,097,152
  __hip_bfloat16* WkvT = (__hip_bfloat16*)(w + 69206016);   // 4,194,304
  float* kvtmp         = (float*)(w + 73400320);            // 4,194,304
  float* ao            = (float*)(w + 77594624);            // 1,048,576
  __hip_bfloat16* Mt   = (__hip_bfloat16*)(w + 78643200);   // 8,388,608

  cvt_x_kernel<<<2048, 256, 0, stream>>>(x, xb, 16777216 / 4);

  transpose_cvt3<<<dim3(32, 32, 3), dim3(32, 8), 0, stream>>>(
      Wg, Wk, Wv, WgT, WkvT, WkvT + 1024 * 1024);

  // gates: G = softmax_groups(x @ Wg), bf16  [16384,1024]
  gemm256<1><<<dim3(64, 4, 1), 512, 0, stream>>>(xb, WgT, G, 1024, 1024, 0LL, 0LL, 0LL);

  // k,v for t<128 (only t<64 used): kvtmp[b][t][0:1024]=k, [1024:2048]=v (fp32)
  gemm_bt<<<dim3(1, 16, 4), 256, 0, stream>>>(xb, WkvT, kvtmp, 1024, 2048,
                                              4096LL * 1024, 0LL, 128LL * 2048);

  attn_kernel<<<dim3(16, 4), 256, 0, stream>>>(kvtmp, lq, ao);

  build_mt<<<dim3(4, 16, 4), 256, 0, stream>>>(ao, Wp, Mt);

  // out[b] = G[b] @ Mt[b]^T  (fp32 out)
  gemm256<0><<<dim3(16, 4, 4), 512, 0, stream>>>(G, Mt, out, 1024, 1024,
                                                 4096LL * 1024, 1024LL * 1024, 4096LL * 1024);
}

// Round 5
// 166.106 us; speedup vs baseline: 1.1549x; 1.1549x over previous
//
#include <hip/hip_runtime.h>
#include <hip/hip_bf16.h>

// MultiLatentAttention on MI355X.
// causal mask t<=l with L=64 => attention only over first 64 tokens.
// out[b] = softmax_groups(x@Wg) @ M[b],  M built from attn_out and Wp.

typedef __attribute__((ext_vector_type(8))) short bf16x8;
typedef __attribute__((ext_vector_type(4))) float f32x4;
typedef __attribute__((ext_vector_type(4))) unsigned short us4;

__device__ __forceinline__ void gll16(const void* g, void* l) {
  __builtin_amdgcn_global_load_lds((const __attribute__((address_space(1))) void*)g,
                                   (__attribute__((address_space(3))) void*)l, 16, 0, 0);
}

// ---------------- x (fp32) -> bf16 ----------------
__global__ void cvt_x_kernel(const float* __restrict__ x, __hip_bfloat16* __restrict__ xb, int n4) {
  int stride = gridDim.x * blockDim.x;
  for (int i = blockIdx.x * blockDim.x + threadIdx.x; i < n4; i += stride) {
    float4 f = reinterpret_cast<const float4*>(x)[i];
    union { __hip_bfloat16 h[4]; us4 v; } u;
    u.h[0] = __float2bfloat16(f.x);
    u.h[1] = __float2bfloat16(f.y);
    u.h[2] = __float2bfloat16(f.z);
    u.h[3] = __float2bfloat16(f.w);
    reinterpret_cast<us4*>(xb)[i] = u.v;
  }
}

// ---------------- 3 weight transposes fp32->bf16 in one launch ----------------
__global__ void transpose_cvt3(const float* __restrict__ Wg, const float* __restrict__ Wk,
                               const float* __restrict__ Wv,
                               __hip_bfloat16* __restrict__ WgT, __hip_bfloat16* __restrict__ WkT,
                               __hip_bfloat16* __restrict__ WvT) {
  const int n = 1024;
  const float* W;
  __hip_bfloat16* Wt;
  if (blockIdx.z == 0)      { W = Wg; Wt = WgT; }
  else if (blockIdx.z == 1) { W = Wk; Wt = WkT; }
  else                      { W = Wv; Wt = WvT; }
  __shared__ float tile[32][33];
  int bx = blockIdx.x * 32, by = blockIdx.y * 32;
  int tx = threadIdx.x, ty = threadIdx.y;  // block (32,8)
  #pragma unroll
  for (int j = 0; j < 32; j += 8)
    tile[ty + j][tx] = W[(size_t)(by + ty + j) * n + bx + tx];
  __syncthreads();
  #pragma unroll
  for (int j = 0; j < 32; j += 8)
    Wt[(size_t)(bx + ty + j) * n + by + tx] = __float2bfloat16(tile[tx][ty + j]);
}

// ---------------- 256x256 2-phase pipelined bf16 GEMM: C = A @ Bt^T ----------------
// (proven round-3 version, ~49us @ 16384x1024x1024) — used for the gates GEMM.
// EPI=1: per-64-column-group softmax, bf16 store (gates).
template <int EPI>
__global__ __launch_bounds__(512, 2)
void gemm256(const __hip_bfloat16* __restrict__ A, const __hip_bfloat16* __restrict__ Bt,
             void* __restrict__ Cv, int K, int ldc,
             long long astride, long long bstride, long long cstride) {
  __shared__ __align__(16) unsigned short SA[2][256 * 64];
  __shared__ __align__(16) unsigned short SB[2][256 * 64];
  const int tid = threadIdx.x;
  const int lane = tid & 63;
  const int w = tid >> 6;            // wave 0..7
  const int wm = w >> 2, wn = w & 3; // 2x4 wave grid; per-wave out = 128x64
  const int lr = lane & 15, lk = lane >> 4;
  const int m0 = blockIdx.x * 256, n0 = blockIdx.y * 256;
  const long long b = blockIdx.z;
  const __hip_bfloat16* Ab = A + b * astride;
  const __hip_bfloat16* Bb = Bt + b * bstride;

  f32x4 acc[8][4] = {};

  const int NT = K >> 6;
  int buf = 0;

  auto STAGE = [&](int bsel, int kt) {
    #pragma unroll
    for (int r = 0; r < 4; ++r) {
      int c = r * 512 + tid;          // chunk 0..2047: row=c>>3, slot=c&7
      int row = c >> 3, slot = c & 7;
      int gch = slot ^ (row & 7);     // pre-swizzled global chunk
      gll16(Ab + (size_t)(m0 + row) * K + kt + gch * 8, (char*)&SA[bsel][0] + c * 16);
      gll16(Bb + (size_t)(n0 + row) * K + kt + gch * 8, (char*)&SB[bsel][0] + c * 16);
    }
  };

  STAGE(0, 0);
  __syncthreads();

  for (int t = 0; t < NT; ++t) {
    if (t + 1 < NT) STAGE(buf ^ 1, (t + 1) << 6);

    bf16x8 bfr[2][4];
    #pragma unroll
    for (int kk = 0; kk < 2; ++kk)
      #pragma unroll
      for (int ni = 0; ni < 4; ++ni) {
        int row = wn * 64 + ni * 16 + lr;
        int ch = (kk * 4 + lk) ^ (row & 7);
        bfr[kk][ni] = *(const bf16x8*)&SB[buf][row * 64 + ch * 8];
      }
    #pragma unroll
    for (int mi = 0; mi < 8; ++mi) {
      int row = wm * 128 + mi * 16 + lr;
      int ch0 = lk ^ (row & 7);
      int ch1 = (4 + lk) ^ (row & 7);
      bf16x8 a0 = *(const bf16x8*)&SA[buf][row * 64 + ch0 * 8];
      bf16x8 a1 = *(const bf16x8*)&SA[buf][row * 64 + ch1 * 8];
      #pragma unroll
      for (int ni = 0; ni < 4; ++ni)
        acc[mi][ni] = __builtin_amdgcn_mfma_f32_16x16x32_bf16(a0, bfr[0][ni], acc[mi][ni], 0, 0, 0);
      #pragma unroll
      for (int ni = 0; ni < 4; ++ni)
        acc[mi][ni] = __builtin_amdgcn_mfma_f32_16x16x32_bf16(a1, bfr[1][ni], acc[mi][ni], 0, 0, 0);
    }
    __syncthreads();
    buf ^= 1;
  }

  if (EPI == 0) {
    float* C = (float*)Cv + b * cstride;
    #pragma unroll
    for (int mi = 0; mi < 8; ++mi) {
      int r = m0 + wm * 128 + mi * 16 + lk * 4;
      #pragma unroll
      for (int ni = 0; ni < 4; ++ni) {
        int c = n0 + wn * 64 + ni * 16 + lr;
        #pragma unroll
        for (int jj = 0; jj < 4; ++jj)
          C[(size_t)(r + jj) * ldc + c] = acc[mi][ni][jj];
      }
    }
  } else {
    // Each wave's 64 columns = one softmax group (head h, l=0..63).
    __hip_bfloat16* C = (__hip_bfloat16*)Cv + b * cstride;
    #pragma unroll
    for (int mi = 0; mi < 8; ++mi) {
      #pragma unroll
      for (int jj = 0; jj < 4; ++jj) {
        float mx = -3.0e38f;
        #pragma unroll
        for (int ni = 0; ni < 4; ++ni) mx = fmaxf(mx, acc[mi][ni][jj]);
        mx = fmaxf(mx, __shfl_xor(mx, 1));
        mx = fmaxf(mx, __shfl_xor(mx, 2));
        mx = fmaxf(mx, __shfl_xor(mx, 4));
        mx = fmaxf(mx, __shfl_xor(mx, 8));
        float e[4];
        float s = 0.f;
        #pragma unroll
        for (int ni = 0; ni < 4; ++ni) { e[ni] = __expf(acc[mi][ni][jj] - mx); s += e[ni]; }
        s += __shfl_xor(s, 1);
        s += __shfl_xor(s, 2);
        s += __shfl_xor(s, 4);
        s += __shfl_xor(s, 8);
        float inv = 1.0f / s;
        int r = m0 + wm * 128 + mi * 16 + lk * 4 + jj;
        #pragma unroll
        for (int ni = 0; ni < 4; ++ni)
          C[(size_t)r * ldc + n0 + wn * 64 + ni * 16 + lr] = __float2bfloat16(e[ni] * inv);
      }
    }
  }
}

// ---------------- 256x256 8-phase GEMM v2 (corrected schedule) ----------------
// Quadrant order per K-tile: (0,0)(1,0)(0,1)(1,1); A-frags for both M-halves held
// across the tile's 4 phases (reads/phase: 12/8/4/0). One stage unit (2 gll16/thread,
// = one 128row x 64K half) per phase. Stage slots / deadlines (iter computes T0=buf0
// P1-4, T1=buf1 P5-8):
//   P1:T1.A0  P2:T1.A1  P3:T1.B1  P4:T2.B0  P5:T2.A0  P6:T2.A1  P7:T2.B1  P8:T3.B0
//   (T1.B0 was staged at prev-P8.)  Region free-windows verified: B0 read P1,P2;
//   B1 read P3,P4; A read P1-P4 (per buf).
// Counted waits (never 0 in-loop), placed after MFMA before phase-end barrier:
//   end-P2: vmcnt(6) [covers T0.B1 <- prev-P7]   end-P4: vmcnt(4) [T1.A0,A1,B0]
//   end-P6: vmcnt(6) [T1.B1 <- P3]               end-P8: vmcnt(4) [T2.B0,A0,A1]
// Raw s_barrier, NO sched_barrier; plain C++ ds_reads (compiler emits lgkm waits);
// the vmcnt asm memory-clobbers pin stage/read motion across the critical barriers.
#define VMW(N) asm volatile("s_waitcnt vmcnt(" #N ")" ::: "memory")
#define BAR __builtin_amdgcn_s_barrier()

__global__ __launch_bounds__(512, 2)
void gemm256_8p(const __hip_bfloat16* __restrict__ A, const __hip_bfloat16* __restrict__ Bt,
                float* __restrict__ Cv, int K, int ldc,
                long long astride, long long bstride, long long cstride) {
  __shared__ __align__(16) unsigned short SA[2][256 * 64];
  __shared__ __align__(16) unsigned short SB[2][256 * 64];
  const int tid = threadIdx.x;
  const int lane = tid & 63;
  const int w = tid >> 6;
  const int wm = w >> 2, wn = w & 3;
  const int lr = lane & 15, lk = lane >> 4;
  const int m0 = blockIdx.x * 256, n0 = blockIdx.y * 256;
  const long long b = blockIdx.z;
  const __hip_bfloat16* Ab = A + b * astride;
  const __hip_bfloat16* Bb = Bt + b * bstride;

  f32x4 acc[8][4] = {};
  bf16x8 afr0[4][2], afr1[4][2], bfr[2][2];

  auto stageA = [&](int bsel, int kt, int half) {
    #pragma unroll
    for (int r = 0; r < 2; ++r) {
      int c = half * 1024 + r * 512 + tid;
      int row = c >> 3, slot = c & 7;
      int gch = slot ^ (row & 7);
      gll16(Ab + (size_t)(m0 + row) * K + kt + gch * 8, (char*)&SA[bsel][0] + c * 16);
    }
  };
  auto stageB = [&](int bsel, int kt, int q) {
    #pragma unroll
    for (int r = 0; r < 2; ++r) {
      int j = r * 2 + (tid >> 8);
      int c = j * 512 + q * 256 + (tid & 255);
      int row = c >> 3, slot = c & 7;
      int gch = slot ^ (row & 7);
      gll16(Bb + (size_t)(n0 + row) * K + kt + gch * 8, (char*)&SB[bsel][0] + c * 16);
    }
  };
  auto loadA = [&](bf16x8 (&af)[4][2], int bsel, int qm) {
    #pragma unroll
    for (int i = 0; i < 4; ++i)
      #pragma unroll
      for (int kk = 0; kk < 2; ++kk) {
        int row = wm * 128 + (qm * 4 + i) * 16 + lr;
        int ch = (kk * 4 + lk) ^ (row & 7);
        af[i][kk] = *(const bf16x8*)&SA[bsel][row * 64 + ch * 8];
      }
  };
  auto loadB = [&](int bsel, int qn) {
    #pragma unroll
    for (int j = 0; j < 2; ++j)
      #pragma unroll
      for (int kk = 0; kk < 2; ++kk) {
        int row = wn * 64 + (qn * 2 + j) * 16 + lr;
        int ch = (kk * 4 + lk) ^ (row & 7);
        bfr[j][kk] = *(const bf16x8*)&SB[bsel][row * 64 + ch * 8];
      }
  };
  auto mfmaQ = [&](bf16x8 (&af)[4][2], int qm, int qn) {
    __builtin_amdgcn_s_setprio(1);
    #pragma unroll
    for (int kk = 0; kk < 2; ++kk)
      #pragma unroll
      for (int i = 0; i < 4; ++i)
        #pragma unroll
        for (int j = 0; j < 2; ++j)
          acc[qm * 4 + i][qn * 2 + j] = __builtin_amdgcn_mfma_f32_16x16x32_bf16(
              af[i][kk], bfr[j][kk], acc[qm * 4 + i][qn * 2 + j], 0, 0, 0);
    __builtin_amdgcn_s_setprio(0);
  };

  // prologue: T0 fully (B0,B1,A0,A1) into buf0, T1.B0 into buf1
  stageB(0, 0, 0);
  stageB(0, 0, 1);
  stageA(0, 0, 0);
  stageA(0, 0, 1);
  stageB(1, 64, 0);
  VMW(2);
  BAR;

  const int NITER = K >> 7;
  for (int it = 0; it < NITER; ++it) {
    int t1k = it * 128 + 64;
    int t2k = it * 128 + 128; if (t2k >= K) t2k -= K;  // wrap: garbage re-stage, window-safe
    int t3k = it * 128 + 192; if (t3k >= K) t3k -= K;

    // P1 (buf0, Q(0,0))
    loadA(afr0, 0, 0); loadB(0, 0); stageA(1, t1k, 0); BAR;
    mfmaQ(afr0, 0, 0); BAR;
    // P2 (buf0, Q(1,0))
    loadA(afr1, 0, 1); stageA(1, t1k, 1); BAR;
    mfmaQ(afr1, 1, 0); VMW(6); BAR;
    // P3 (buf0, Q(0,1))
    loadB(0, 1); stageB(1, t1k, 1); BAR;
    mfmaQ(afr0, 0, 1); BAR;
    // P4 (buf0, Q(1,1))
    stageB(0, t2k, 0); BAR;
    mfmaQ(afr1, 1, 1); VMW(4); BAR;
    // P5 (buf1, Q(0,0))
    loadA(afr0, 1, 0); loadB(1, 0); stageA(0, t2k, 0); BAR;
    mfmaQ(afr0, 0, 0); BAR;
    // P6 (buf1, Q(1,0))
    loadA(afr1, 1, 1); stageA(0, t2k, 1); BAR;
    mfmaQ(afr1, 1, 0); VMW(6); BAR;
    // P7 (buf1, Q(0,1))
    loadB(1, 1); stageB(0, t2k, 1); BAR;
    mfmaQ(afr0, 0, 1); BAR;
    // P8 (buf1, Q(1,1))
    stageB(1, t3k, 0); BAR;
    mfmaQ(afr1, 1, 1); VMW(4); BAR;
  }
  asm volatile("s_waitcnt vmcnt(0)" ::: "memory");  // drain tail garbage stages

  float* C = Cv + b * cstride;
  #pragma unroll
  for (int mi = 0; mi < 8; ++mi) {
    int r = m0 + wm * 128 + mi * 16 + lk * 4;
    #pragma unroll
    for (int ni = 0; ni < 4; ++ni) {
      int c = n0 + wn * 64 + ni * 16 + lr;
      #pragma unroll
      for (int jj = 0; jj < 4; ++jj)
        C[(size_t)(r + jj) * ldc + c] = acc[mi][ni][jj];
    }
  }
}

// ---------------- 128x128 GEMM (kept for the small kv projection) ----------------
__global__ __launch_bounds__(256)
void gemm_bt(const __hip_bfloat16* __restrict__ A, const __hip_bfloat16* __restrict__ Bt,
             void* __restrict__ Cv, int K, int ldc,
             long long astride, long long bstride, long long cstride) {
  __shared__ __align__(16) unsigned short As[128 * 32];
  __shared__ __align__(16) unsigned short Bs[128 * 32];
  const int tid = threadIdx.x;
  const int lane = tid & 63;
  const int w = tid >> 6;
  const int wm = w >> 1, wn = w & 1;
  const int lr = lane & 15, lk = lane >> 4;
  const int m0 = blockIdx.x * 128, n0 = blockIdx.y * 128;
  const long long b = blockIdx.z;
  const __hip_bfloat16* Ab = A + b * astride;
  const __hip_bfloat16* Bb = Bt + b * bstride;

  f32x4 acc[4][4] = {};
  const int r0 = tid >> 2;
  const int c8 = (tid & 3) * 8;

  for (int kt = 0; kt < K; kt += 32) {
    __syncthreads();
    gll16(Ab + (size_t)(m0 + r0) * K + kt + c8,       (char*)As + (w * 64) * 16);
    gll16(Bb + (size_t)(n0 + r0) * K + kt + c8,       (char*)Bs + (w * 64) * 16);
    gll16(Ab + (size_t)(m0 + 64 + r0) * K + kt + c8,  (char*)As + (256 + w * 64) * 16);
    gll16(Bb + (size_t)(n0 + 64 + r0) * K + kt + c8,  (char*)Bs + (256 + w * 64) * 16);
    __syncthreads();

    bf16x8 af[4], bf[4];
    #pragma unroll
    for (int mi = 0; mi < 4; ++mi)
      af[mi] = *(const bf16x8*)&As[(wm * 64 + mi * 16 + lr) * 32 + lk * 8];
    #pragma unroll
    for (int ni = 0; ni < 4; ++ni)
      bf[ni] = *(const bf16x8*)&Bs[(wn * 64 + ni * 16 + lr) * 32 + lk * 8];
    #pragma unroll
    for (int mi = 0; mi < 4; ++mi)
      #pragma unroll
      for (int ni = 0; ni < 4; ++ni)
        acc[mi][ni] = __builtin_amdgcn_mfma_f32_16x16x32_bf16(af[mi], bf[ni], acc[mi][ni], 0, 0, 0);
  }

  float* C = (float*)Cv + b * cstride;
  #pragma unroll
  for (int mi = 0; mi < 4; ++mi) {
    int r = m0 + wm * 64 + mi * 16 + lk * 4;
    #pragma unroll
    for (int ni = 0; ni < 4; ++ni) {
      int c = n0 + wn * 64 + ni * 16 + lr;
      #pragma unroll
      for (int jj = 0; jj < 4; ++jj)
        C[(size_t)(r + jj) * ldc + c] = acc[mi][ni][jj];
    }
  }
}

// ---------------- attention (RoPE fused into K staging): per (b,h), 64x64 ----------------
__global__ __launch_bounds__(256)
void attn_kernel(const float* __restrict__ kv, const float* __restrict__ lq,
                 float* __restrict__ ao) {
  int h = blockIdx.x, b = blockIdx.y;
  __shared__ float Ks[64][64];
  __shared__ float Vs[64][64];
  __shared__ float S[64][65];   // S[l][t]
  __shared__ float Pt[64][65];  // Pt[t][l]
  const int tid = threadIdx.x;
  const float* kb = kv + (size_t)b * 128 * 2048 + h * 64;
  const float* vb = kb + 1024;

  {
    int r = tid >> 4;            // 0..15
    int c4 = (tid & 15) * 4;     // head-dim col (pairs i0=c4/2, i0+1)
    int i0 = c4 >> 1;
    float inv0 = exp2f(-13.287712379549449f * ((float)i0 * (1.0f / 32.0f)));
    float inv1 = exp2f(-13.287712379549449f * ((float)(i0 + 1) * (1.0f / 32.0f)));
    #pragma unroll
    for (int j = 0; j < 4; ++j) {
      int row = j * 16 + r;      // t
      float4 kf = *(const float4*)&kb[(size_t)row * 2048 + c4];
      float a0 = (float)row * inv0, a1 = (float)row * inv1;
      float s0 = sinf(a0), c0 = cosf(a0), s1 = sinf(a1), c1 = cosf(a1);
      *(float4*)&Ks[row][c4] = make_float4(kf.x * c0 - kf.y * s0, kf.x * s0 + kf.y * c0,
                                           kf.z * c1 - kf.w * s1, kf.z * s1 + kf.w * c1);
      *(float4*)&Vs[row][c4] = *(const float4*)&vb[(size_t)row * 2048 + c4];
    }
  }
  __syncthreads();

  // ---- scores: thread = (l = lane, t-chunk = wave) ----
  {
    const int w = tid >> 6, l = tid & 63;
    float q[64];
    const float4* lq4 = (const float4*)(lq + ((size_t)l * 16 + h) * 64);
    #pragma unroll
    for (int i = 0; i < 16; ++i) {
      float4 f = lq4[i];
      q[4 * i] = f.x; q[4 * i + 1] = f.y; q[4 * i + 2] = f.z; q[4 * i + 3] = f.w;
    }
    #pragma unroll
    for (int tl = 0; tl < 16; ++tl) {
      int t = w * 16 + tl;
      float acc = 0.f;
      #pragma unroll
      for (int d4 = 0; d4 < 16; ++d4) {
        float4 kf = *(const float4*)&Ks[t][d4 * 4];
        acc += q[4 * d4] * kf.x + q[4 * d4 + 1] * kf.y + q[4 * d4 + 2] * kf.z + q[4 * d4 + 3] * kf.w;
      }
      S[l][t] = acc * 0.125f;
    }
  }
  __syncthreads();

  // ---- softmax: thread = (l = tid>>2, c = tid&3), causal t<=l ----
  {
    const int l = tid >> 2, c = tid & 3;
    float sv[16];
    float mx = -3.0e38f;
    #pragma unroll
    for (int i = 0; i < 16; ++i) {
      int t = c * 16 + i;
      sv[i] = S[l][t];
      if (t <= l) mx = fmaxf(mx, sv[i]);
    }
    mx = fmaxf(mx, __shfl_xor(mx, 1));
    mx = fmaxf(mx, __shfl_xor(mx, 2));
    float sum = 0.f;
    float e[16];
    #pragma unroll
    for (int i = 0; i < 16; ++i) {
      int t = c * 16 + i;
      e[i] = (t <= l) ? __expf(sv[i] - mx) : 0.f;
      sum += e[i];
    }
    sum += __shfl_xor(sum, 1);
    sum += __shfl_xor(sum, 2);
    float inv = 1.0f / sum;
    #pragma unroll
    for (int i = 0; i < 16; ++i) Pt[c * 16 + i][l] = e[i] * inv;
  }
  __syncthreads();

  // ---- PV: thread = (l = lane, d-chunk = wave) ----
  {
    const int w = tid >> 6, l = tid & 63;
    float o[16];
    #pragma unroll
    for (int i = 0; i < 16; ++i) o[i] = 0.f;
    for (int t = 0; t < 64; ++t) {
      float p = Pt[t][l];
      #pragma unroll
      for (int d4 = 0; d4 < 4; ++d4) {
        float4 vf = *(const float4*)&Vs[t][w * 16 + d4 * 4];
        o[4 * d4]     += p * vf.x;
        o[4 * d4 + 1] += p * vf.y;
        o[4 * d4 + 2] += p * vf.z;
        o[4 * d4 + 3] += p * vf.w;
      }
    }
    float4* dst = (float4*)(ao + (((size_t)b * 16 + h) * 64 + l) * 64 + w * 16);
    #pragma unroll
    for (int d4 = 0; d4 < 4; ++d4)
      dst[d4] = make_float4(o[4 * d4], o[4 * d4 + 1], o[4 * d4 + 2], o[4 * d4 + 3]);
  }
}

// ---------------- Mt[b][c][h*64+l] = sum_d ao[b,h,l,d] * Wp[h*64+d][c]  (bf16) ----------------
__global__ void build_mt(const float* __restrict__ ao, const float* __restrict__ Wp,
                         __hip_bfloat16* __restrict__ Mt) {
  int ct = blockIdx.x;  // 0..3
  int h = blockIdx.y;   // 0..15
  int b = blockIdx.z;   // 0..3
  int c = ct * 256 + threadIdx.x;
  __shared__ float A[64][64];  // ao[l][d]
  const float* aob = ao + (((size_t)b * 16 + h) * 64) * 64;
  for (int i = threadIdx.x; i < 4096; i += 256) A[i >> 6][i & 63] = aob[i];
  __syncthreads();
  for (int lc = 0; lc < 4; ++lc) {
    float acc[16];
    #pragma unroll
    for (int li = 0; li < 16; ++li) acc[li] = 0.f;
    for (int d = 0; d < 64; ++d) {
      float wv = Wp[(size_t)(h * 64 + d) * 1024 + c];
      #pragma unroll
      for (int li = 0; li < 16; ++li) acc[li] += A[lc * 16 + li][d] * wv;
    }
    size_t base = ((size_t)b * 1024 + c) * 1024 + h * 64 + lc * 16;
    #pragma unroll
    for (int li = 0; li < 16; ++li) Mt[base + li] = __float2bfloat16(acc[li]);
  }
}

extern "C" void kernel_launch(void* const* d_in, const int* in_sizes, int n_in,
                              void* d_out, int out_size, void* d_ws, size_t ws_size,
                              hipStream_t stream) {
  const float* x  = (const float*)d_in[0];
  const float* lq = (const float*)d_in[1];
  const float* Wk = (const float*)d_in[2];
  const float* Wv = (const float*)d_in[3];
  const float* Wg = (const float*)d_in[4];
  const float* Wp = (const float*)d_in[5];
  float* out = (float*)d_out;

  // workspace layout (bytes)
  char* w = (char*)d_ws;
  __hip_bfloat16* xb   = (__hip_bfloat16*)(w);              // 33,554,432
  __hip_bfloat16* G    = (__hip_bfloat16*)(w + 33554432);   // 33,554,432
  __hip_bfloat16* WgT  = (__hip_bfloat16*)(w + 67108864);   // 2,097,152
  __hip_bfloat16* WkvT = (__hip_bfloat16*)(w + 69206016);   // 4,194,304
  float* kvtmp         = (float*)(w + 73400320);            // 4,194,304
  float* ao            = (float*)(w + 77594624);            // 1,048,576
  __hip_bfloat16* Mt   = (__hip_bfloat16*)(w + 78643200);   // 8,388,608

  cvt_x_kernel<<<2048, 256, 0, stream>>>(x, xb, 16777216 / 4);

  transpose_cvt3<<<dim3(32, 32, 3), dim3(32, 8), 0, stream>>>(
      Wg, Wk, Wv, WgT, WkvT, WkvT + 1024 * 1024);

  // gates: G = softmax_groups(x @ Wg), bf16  [16384,1024]  -- 2-phase (A)
  gemm256<1><<<dim3(64, 4, 1), 512, 0, stream>>>(xb, WgT, G, 1024, 1024, 0LL, 0LL, 0LL);

  // k,v for t<128 (only t<64 used): kvtmp[b][t][0:1024]=k, [1024:2048]=v (fp32)
  gemm_bt<<<dim3(1, 16, 4), 256, 0, stream>>>(xb, WkvT, kvtmp, 1024, 2048,
                                              4096LL * 1024, 0LL, 128LL * 2048);

  attn_kernel<<<dim3(16, 4), 256, 0, stream>>>(kvtmp, lq, ao);

  build_mt<<<dim3(4, 16, 4), 256, 0, stream>>>(ao, Wp, Mt);

  // out[b] = G[b] @ Mt[b]^T  (fp32 out) -- 8-phase v2 (B of the A/B)
  gemm256_8p<<<dim3(16, 4, 4), 512, 0, stream>>>(G, Mt, out, 1024, 1024,
                                                 4096LL * 1024, 1024LL * 1024, 4096LL * 1024);
}